// Round 11
// baseline (563.946 us; speedup 1.0000x reference)
//
#include <hip/hip_runtime.h>
#include <hip/hip_fp16.h>
#include <math.h>

// Problem constants (from reference)
#define N_NODES 50000
#define IN_DIM  128
#define HIDDEN  64
#define OUT_DIM 10
#define HEADS   4
#define E_RAW   800000
#define E_TOT   (E_RAW + N_NODES)   // with self-loops: 850000
#define NEG_SLOPE 0.2f

#define NB_SCAN 196   // ceil(50000/256)
#define NB_EDGE 3321  // ceil(850000/256)
#define NB_GEMM 782   // ceil(50000/64)

// ---------------- edge_index dtype detection ----------------
// flag[0] == 1  =>  int32 layout (shift 0);  flag[0] == 0  =>  int64 (shift 1).
__global__ void detect_i32(const int* __restrict__ ei, int* __restrict__ flag) {
    int t = threadIdx.x;                      // single block of 256
    int idx = 2 * (t * 3100 + 17) + 1;        // odd, < 1.6M for t < 256
    if (ei[idx] != 0) atomicOr(flag, 1);
}

// ---------------- CSR build ----------------

__global__ void zero_counts(int* __restrict__ counts, int* __restrict__ flag) {
    int i = blockIdx.x * 256 + threadIdx.x;
    if (i < N_NODES) counts[i] = 0;
    if (i == 0) flag[0] = 0;
}

__global__ void count_edges(const int* __restrict__ ei, int* __restrict__ counts,
                            const int* __restrict__ flag) {
    int t = blockIdx.x * 256 + threadIdx.x;
    if (t >= E_TOT) return;
    int sh = flag[0] ? 0 : 1;                 // int32 -> 0, int64 -> 1 (low word)
    int dst = (t < E_RAW) ? ei[(E_RAW + t) << sh] : (t - E_RAW);
    atomicAdd(&counts[dst], 1);
}

__global__ void scan1(const int* __restrict__ counts, int* __restrict__ indptr,
                      int* __restrict__ bsums) {
    __shared__ int sd[256];
    int t = threadIdx.x;
    int i = blockIdx.x * 256 + t;
    int v = (i < N_NODES) ? counts[i] : 0;
    sd[t] = v;
    __syncthreads();
    for (int o = 1; o < 256; o <<= 1) {
        int x = (t >= o) ? sd[t - o] : 0;
        __syncthreads();
        sd[t] += x;
        __syncthreads();
    }
    int incl = sd[t];
    if (i < N_NODES) indptr[i] = incl - v;   // block-local exclusive
    if (t == 255) bsums[blockIdx.x] = incl;  // block total
}

__global__ void scan2(int* __restrict__ bsums) {
    __shared__ int sd[256];
    int t = threadIdx.x;
    int v = (t < NB_SCAN) ? bsums[t] : 0;
    sd[t] = v;
    __syncthreads();
    for (int o = 1; o < 256; o <<= 1) {
        int x = (t >= o) ? sd[t - o] : 0;
        __syncthreads();
        sd[t] += x;
        __syncthreads();
    }
    if (t < NB_SCAN) bsums[t] = sd[t] - v;   // exclusive block offsets
}

__global__ void scan3(int* __restrict__ indptr, const int* __restrict__ bsums,
                      int* __restrict__ cursor) {
    int i = blockIdx.x * 256 + threadIdx.x;
    if (i < N_NODES) {
        int v = indptr[i] + bsums[blockIdx.x];
        indptr[i] = v;
        cursor[i] = v;
    }
    if (i == 0) indptr[N_NODES] = E_TOT;
}

__global__ void fill_edges(const int* __restrict__ ei, int* __restrict__ cursor,
                           int* __restrict__ esrc, int* __restrict__ edst,
                           const int* __restrict__ flag) {
    int t = blockIdx.x * 256 + threadIdx.x;
    if (t >= E_TOT) return;
    int sh = flag[0] ? 0 : 1;
    int src, dst;
    if (t < E_RAW) { src = ei[t << sh]; dst = ei[(E_RAW + t) << sh]; }
    else           { src = t - E_RAW; dst = src; }
    int pos = atomicAdd(&cursor[dst], 1);
    esrc[pos] = src;
    edst[pos] = dst;
}

// ---------------- GEMM + attention logits (pipelined 64-row tile) ----------
// Tile 64 rows x 256 cols, 256 threads; thread (da2=t&31, rg=t>>5) owns rows
// rg*8..+7, cols {h*64 + da2*2 +0,1} -> acc[8][8].
// K-loop SOFTWARE-PIPELINED in 16-k chunks with LDS double buffer:
// prefetch chunk c+1 into REGISTERS during compute of chunk c, then regs->LDS,
// ONE barrier per chunk (r10 had stage->barrier->compute: every wave ate the
// full global-load latency per chunk; VALUBusy 41%, occupancy 20%).
// LDS: xs 2x4 KB + wsh 2x16 KB = 40 KB -> 4 blocks/CU.
template <int K>
__global__ void __launch_bounds__(256) gemm_al(
    const float* __restrict__ X, const float* __restrict__ W,
    const float* __restrict__ asrc, const float* __restrict__ adst,
    __half* __restrict__ H, float* __restrict__ AL) {
    __shared__ float xs_t[2][16 * 64];   // [buf][k-in-chunk][row]
    __shared__ float wsh[2][16 * 256];   // [buf][k-in-chunk][col]
    const int NCH = K / 16;
    const int K4 = K / 4;
    int t = threadIdx.x;
    int n0 = blockIdx.x * 64;

    int da2 = t & 31;          // dim pair: d0 = da2*2
    int rg  = t >> 5;          // row group: r0 = rg*8
    int d0 = da2 * 2;
    int r0 = rg * 8;

    int xr = t & 63;           // staging row for this thread
    int xj = t >> 6;           // staging k4-slot (0..3) per chunk
    int xn = n0 + xr; if (xn >= N_NODES) xn = N_NODES - 1;
    const float4* X4 = (const float4*)X;

    float acc[8][8];
#pragma unroll
    for (int i = 0; i < 8; i++)
#pragma unroll
        for (int j = 0; j < 8; j++) acc[i][j] = 0.f;

    // stage chunk 0
    {
        float4 xv = X4[(size_t)xn * K4 + xj];
        xs_t[0][(4 * xj + 0) * 64 + xr] = xv.x;
        xs_t[0][(4 * xj + 1) * 64 + xr] = xv.y;
        xs_t[0][(4 * xj + 2) * 64 + xr] = xv.z;
        xs_t[0][(4 * xj + 3) * 64 + xr] = xv.w;
        const float4* Wc = (const float4*)W;
        float4* dst = (float4*)wsh[0];
#pragma unroll
        for (int m = 0; m < 4; m++) dst[t + 256 * m] = Wc[t + 256 * m];
    }
    __syncthreads();

    for (int c = 0; c < NCH; c++) {
        int cur = c & 1;
        bool more = (c + 1 < NCH);    // wave-uniform
        float4 xv; float4 wv[4];
        if (more) {                   // issue prefetch loads (latency hidden
            xv = X4[(size_t)xn * K4 + (c + 1) * 4 + xj];   //  under compute)
            const float4* Wc = (const float4*)(W + (c + 1) * 16 * 256);
#pragma unroll
            for (int m = 0; m < 4; m++) wv[m] = Wc[t + 256 * m];
        }
        const float* xsC = xs_t[cur];
        const float2* wshC = (const float2*)wsh[cur];
#pragma unroll 4
        for (int k = 0; k < 16; k++) {
            float4 xa = *(const float4*)&xsC[k * 64 + r0];
            float4 xb = *(const float4*)&xsC[k * 64 + r0 + 4];
#pragma unroll
            for (int h = 0; h < 4; h++) {
                float2 w = wshC[k * 128 + h * 32 + da2];
                acc[0][2*h] += xa.x * w.x; acc[0][2*h+1] += xa.x * w.y;
                acc[1][2*h] += xa.y * w.x; acc[1][2*h+1] += xa.y * w.y;
                acc[2][2*h] += xa.z * w.x; acc[2][2*h+1] += xa.z * w.y;
                acc[3][2*h] += xa.w * w.x; acc[3][2*h+1] += xa.w * w.y;
                acc[4][2*h] += xb.x * w.x; acc[4][2*h+1] += xb.x * w.y;
                acc[5][2*h] += xb.y * w.x; acc[5][2*h+1] += xb.y * w.y;
                acc[6][2*h] += xb.z * w.x; acc[6][2*h+1] += xb.z * w.y;
                acc[7][2*h] += xb.w * w.x; acc[7][2*h+1] += xb.w * w.y;
            }
        }
        if (more) {
            int nxt = cur ^ 1;
            xs_t[nxt][(4 * xj + 0) * 64 + xr] = xv.x;
            xs_t[nxt][(4 * xj + 1) * 64 + xr] = xv.y;
            xs_t[nxt][(4 * xj + 2) * 64 + xr] = xv.z;
            xs_t[nxt][(4 * xj + 3) * 64 + xr] = xv.w;
            float4* dst = (float4*)wsh[nxt];
#pragma unroll
            for (int m = 0; m < 4; m++) dst[t + 256 * m] = wv[m];
            __syncthreads();
        }
    }

    // H store: fp16 dim-major; 8 halfs per row at half-offset d0*4 = 16 B
#pragma unroll
    for (int i = 0; i < 8; i++) {
        int n = n0 + r0 + i;
        if (n < N_NODES) {
            __half2 p[4];
            p[0] = __float22half2_rn(make_float2(acc[i][0], acc[i][2])); // d0 h0,h1
            p[1] = __float22half2_rn(make_float2(acc[i][4], acc[i][6])); // d0 h2,h3
            p[2] = __float22half2_rn(make_float2(acc[i][1], acc[i][3])); // d0+1 h0,h1
            p[3] = __float22half2_rn(make_float2(acc[i][5], acc[i][7])); // d0+1 h2,h3
            *(float4*)(H + (size_t)n * 256 + d0 * 4) = *(float4*)p;
        }
    }

    // AL: per-row per-head dot with asrc/adst, butterfly over 32-lane half.
    const float2* as2 = (const float2*)asrc;
    const float2* ad2 = (const float2*)adst;
#pragma unroll
    for (int half = 0; half < 2; half++) {
        float sp[4][4], dp[4][4];
#pragma unroll
        for (int h = 0; h < 4; h++) {
            float2 av = as2[h * 32 + da2];
            float2 dv = ad2[h * 32 + da2];
#pragma unroll
            for (int ii = 0; ii < 4; ii++) {
                int i = half * 4 + ii;
                sp[ii][h] = acc[i][2*h] * av.x + acc[i][2*h+1] * av.y;
                dp[ii][h] = acc[i][2*h] * dv.x + acc[i][2*h+1] * dv.y;
            }
        }
#pragma unroll
        for (int o = 1; o < 32; o <<= 1) {
#pragma unroll
            for (int ii = 0; ii < 4; ii++)
#pragma unroll
                for (int h = 0; h < 4; h++) {
                    sp[ii][h] += __shfl_xor(sp[ii][h], o, 64);
                    dp[ii][h] += __shfl_xor(dp[ii][h], o, 64);
                }
        }
        if (da2 == 0) {
#pragma unroll
            for (int ii = 0; ii < 4; ii++) {
                int n = n0 + r0 + half * 4 + ii;
                if (n < N_NODES) {
#pragma unroll
                    for (int h = 0; h < 4; h++) {
                        AL[n * 8 + h]     = sp[ii][h];
                        AL[n * 8 + 4 + h] = dp[ii][h];
                    }
                }
            }
        }
    }
}

// ---------------- Per-edge unnormalized attention weights ----------------
// One thread per CSR edge position: EW[p] = exp(leaky(AL_src + AL_dst)).
// No max shift: logits analytically bounded (validated rounds 4-10).
__global__ void __launch_bounds__(256) edge_weights(
    const float* __restrict__ AL, const int* __restrict__ esrc,
    const int* __restrict__ edst, float4* __restrict__ EW) {
    int p = blockIdx.x * 256 + threadIdx.x;
    if (p >= E_TOT) return;
    int s = esrc[p], d = edst[p];
    const float4* AL4 = (const float4*)AL;
    float4 as = AL4[s * 2];        // src logits (4 heads)
    float4 ad = AL4[d * 2 + 1];    // dst logits (4 heads)
    float v0 = as.x + ad.x; v0 = fmaxf(v0, NEG_SLOPE * v0);
    float v1 = as.y + ad.y; v1 = fmaxf(v1, NEG_SLOPE * v1);
    float v2 = as.z + ad.z; v2 = fmaxf(v2, NEG_SLOPE * v2);
    float v3 = as.w + ad.w; v3 = fmaxf(v3, NEG_SLOPE * v3);
    EW[p] = make_float4(__expf(v0), __expf(v1), __expf(v2), __expf(v3));
}

// ---------------- Per-destination aggregation ----------------
// One wave per dst node. Per edge: one wave-uniform 16 B EW broadcast load
// + one 8 B H gather per lane + 4 FMA / 4 add. Near the L2-miss fetch floor.
__global__ void __launch_bounds__(256) aggregate(
    const __half* __restrict__ H, const float4* __restrict__ EW,
    const int* __restrict__ indptr, const int* __restrict__ esrc,
    const float* __restrict__ bias, float* __restrict__ XOUT) {
    int wave = threadIdx.x >> 6, lane = threadIdx.x & 63;
    int n = blockIdx.x * 4 + wave;   // 12500 * 4 == 50000 exactly

    int start = indptr[n], end = indptr[n + 1];
    const float2* H2 = (const float2*)H;    // 64 float2 per node row

    float d0 = 0.f, d1 = 0.f, d2 = 0.f, d3 = 0.f;
    float a0 = 0.f, a1 = 0.f, a2 = 0.f, a3 = 0.f;

#define EDGE_BODY(E, Hv)                                            \
    {                                                               \
        d0 += E.x; d1 += E.y; d2 += E.z; d3 += E.w;                 \
        float2 c01 = __half22float2(((const __half2*)&Hv)[0]);      \
        float2 c23 = __half22float2(((const __half2*)&Hv)[1]);      \
        a0 += E.x * c01.x; a1 += E.y * c01.y;                       \
        a2 += E.z * c23.x; a3 += E.w * c23.y;                       \
    }

    for (int cb = start; cb < end; cb += 64) {
        int cnt = end - cb; if (cnt > 64) cnt = 64;
        int my_s = (lane < cnt) ? esrc[cb + lane] : 0;
        for (int base = 0; base < cnt; base += 4) {
            int m = cnt - base;   // wave-uniform
            int s0 = __shfl(my_s, base, 64);
            int s1 = __shfl(my_s, base + (1 < m ? 1 : 0), 64);
            int s2 = __shfl(my_s, base + (2 < m ? 2 : 0), 64);
            int s3 = __shfl(my_s, base + (3 < m ? 3 : 0), 64);
            float4 E0 = EW[cb + base];                       // uniform -> bcast
            float4 E1 = EW[cb + base + (1 < m ? 1 : 0)];
            float4 E2 = EW[cb + base + (2 < m ? 2 : 0)];
            float4 E3 = EW[cb + base + (3 < m ? 3 : 0)];
            float2 H0 = H2[(s0 << 6) + lane];
            float2 H1 = H2[(s1 << 6) + lane];
            float2 H2v = H2[(s2 << 6) + lane];
            float2 H3 = H2[(s3 << 6) + lane];
            EDGE_BODY(E0, H0);
            if (m > 1) EDGE_BODY(E1, H1);
            if (m > 2) EDGE_BODY(E2, H2v);
            if (m > 3) EDGE_BODY(E3, H3);
        }
    }
#undef EDGE_BODY

    float r = a0 / d0 + a1 / d1 + a2 / d2 + a3 / d3;
    r = 0.25f * r + bias[lane];
    r = r > 0.f ? r : (__expf(r) - 1.f);   // ELU
    XOUT[n * 64 + lane] = r;
}

// ---------------- Final FC ----------------
__global__ void __launch_bounds__(256) fc_kernel(
    const float* __restrict__ X, const float* __restrict__ fcW,
    const float* __restrict__ fcb, float* __restrict__ OUT) {
    __shared__ float ws[64 * 10];
    __shared__ float bs[10];
    int t = threadIdx.x;
    for (int i = t; i < 640; i += 256) ws[i] = fcW[i];   // 640 > blockDim
    if (t < 10) bs[t] = fcb[t];
    __syncthreads();
    int n = blockIdx.x * 256 + t;
    if (n >= N_NODES) return;
    float acc[10];
#pragma unroll
    for (int c = 0; c < 10; c++) acc[c] = bs[c];
    for (int d = 0; d < 64; d++) {
        float x = X[n * 64 + d];
#pragma unroll
        for (int c = 0; c < 10; c++) acc[c] += x * ws[d * 10 + c];
    }
#pragma unroll
    for (int c = 0; c < 10; c++) OUT[n * 10 + c] = acc[c];
}

// ---------------- Launch ----------------
extern "C" void kernel_launch(void* const* d_in, const int* in_sizes, int n_in,
                              void* d_out, int out_size, void* d_ws, size_t ws_size,
                              hipStream_t stream) {
    const float* x     = (const float*)d_in[0];
    const int*   ei    = (const int*)d_in[1];
    const float* W[3]    = {(const float*)d_in[2], (const float*)d_in[6], (const float*)d_in[10]};
    const float* asrc[3] = {(const float*)d_in[3], (const float*)d_in[7], (const float*)d_in[11]};
    const float* adst[3] = {(const float*)d_in[4], (const float*)d_in[8], (const float*)d_in[12]};
    const float* bias[3] = {(const float*)d_in[5], (const float*)d_in[9], (const float*)d_in[13]};
    const float* fcW = (const float*)d_in[14];
    const float* fcb = (const float*)d_in[15];
    float* out = (float*)d_out;

    char* ws = (char*)d_ws;
    size_t off = 0;
    auto alloc = [&](size_t bytes) {
        void* p = ws + off;
        off = (off + bytes + 255) & ~(size_t)255;
        return p;
    };
    __half* H     = (__half*)alloc((size_t)N_NODES * 256 * 2);  // 25.6 MB fp16
    float* AL     = (float*)alloc((size_t)N_NODES * 8 * 4);     // 1.6 MB
    float4* EW    = (float4*)alloc((size_t)E_TOT * 16);         // 13.6 MB
    float* XA     = (float*)alloc((size_t)N_NODES * 64 * 4);    // 12.8 MB
    float* XB     = (float*)alloc((size_t)N_NODES * 64 * 4);    // 12.8 MB
    int*   counts = (int*)alloc((size_t)N_NODES * 4);
    int*   indptr = (int*)alloc((size_t)(N_NODES + 1) * 4);
    int*   cursor = (int*)alloc((size_t)N_NODES * 4);
    int*   esrc   = (int*)alloc((size_t)E_TOT * 4);             // 3.4 MB
    int*   edst   = (int*)alloc((size_t)E_TOT * 4);             // 3.4 MB
    int*   bsums  = (int*)alloc(256 * 4);
    int*   flag   = (int*)alloc(256 * 4);

    // CSR build (graph is identical each call; ws is re-poisoned so rebuild)
    zero_counts<<<NB_SCAN, 256, 0, stream>>>(counts, flag);
    detect_i32<<<1, 256, 0, stream>>>(ei, flag);
    count_edges<<<NB_EDGE, 256, 0, stream>>>(ei, counts, flag);
    scan1<<<NB_SCAN, 256, 0, stream>>>(counts, indptr, bsums);
    scan2<<<1, 256, 0, stream>>>(bsums);
    scan3<<<NB_SCAN, 256, 0, stream>>>(indptr, bsums, cursor);
    fill_edges<<<NB_EDGE, 256, 0, stream>>>(ei, cursor, esrc, edst, flag);

    // Layer 0
    gemm_al<128><<<NB_GEMM, 256, 0, stream>>>(x, W[0], asrc[0], adst[0], H, AL);
    edge_weights<<<NB_EDGE, 256, 0, stream>>>(AL, esrc, edst, EW);
    aggregate<<<N_NODES / 4, 256, 0, stream>>>(H, EW, indptr, esrc, bias[0], XA);
    // Layer 1
    gemm_al<64><<<NB_GEMM, 256, 0, stream>>>(XA, W[1], asrc[1], adst[1], H, AL);
    edge_weights<<<NB_EDGE, 256, 0, stream>>>(AL, esrc, edst, EW);
    aggregate<<<N_NODES / 4, 256, 0, stream>>>(H, EW, indptr, esrc, bias[1], XB);
    // Layer 2
    gemm_al<64><<<NB_GEMM, 256, 0, stream>>>(XB, W[2], asrc[2], adst[2], H, AL);
    edge_weights<<<NB_EDGE, 256, 0, stream>>>(AL, esrc, edst, EW);
    aggregate<<<N_NODES / 4, 256, 0, stream>>>(H, EW, indptr, esrc, bias[2], XA);

    // Final FC
    fc_kernel<<<NB_SCAN, 256, 0, stream>>>(XA, fcW, fcb, out);
}

// Round 12
// 546.555 us; speedup vs baseline: 1.0318x; 1.0318x over previous
//
#include <hip/hip_runtime.h>
#include <hip/hip_fp16.h>
#include <math.h>

// Problem constants (from reference)
#define N_NODES 50000
#define IN_DIM  128
#define HIDDEN  64
#define OUT_DIM 10
#define HEADS   4
#define E_RAW   800000
#define E_TOT   (E_RAW + N_NODES)   // with self-loops: 850000
#define NEG_SLOPE 0.2f

#define NB_SCAN 196    // ceil(50000/256)
#define NB_EDGE 3321   // ceil(850000/256)
#define NB_GEMM 1564   // ceil(50000/64) row-tiles x 2 column-halves

// ---------------- edge_index dtype detection ----------------
// flag[0] == 1  =>  int32 layout (shift 0);  flag[0] == 0  =>  int64 (shift 1).
__global__ void detect_i32(const int* __restrict__ ei, int* __restrict__ flag) {
    int t = threadIdx.x;                      // single block of 256
    int idx = 2 * (t * 3100 + 17) + 1;        // odd, < 1.6M for t < 256
    if (ei[idx] != 0) atomicOr(flag, 1);
}

// ---------------- CSR build ----------------

__global__ void zero_counts(int* __restrict__ counts, int* __restrict__ flag) {
    int i = blockIdx.x * 256 + threadIdx.x;
    if (i < N_NODES) counts[i] = 0;
    if (i == 0) flag[0] = 0;
}

__global__ void count_edges(const int* __restrict__ ei, int* __restrict__ counts,
                            const int* __restrict__ flag) {
    int t = blockIdx.x * 256 + threadIdx.x;
    if (t >= E_TOT) return;
    int sh = flag[0] ? 0 : 1;                 // int32 -> 0, int64 -> 1 (low word)
    int dst = (t < E_RAW) ? ei[(E_RAW + t) << sh] : (t - E_RAW);
    atomicAdd(&counts[dst], 1);
}

__global__ void scan1(const int* __restrict__ counts, int* __restrict__ indptr,
                      int* __restrict__ bsums) {
    __shared__ int sd[256];
    int t = threadIdx.x;
    int i = blockIdx.x * 256 + t;
    int v = (i < N_NODES) ? counts[i] : 0;
    sd[t] = v;
    __syncthreads();
    for (int o = 1; o < 256; o <<= 1) {
        int x = (t >= o) ? sd[t - o] : 0;
        __syncthreads();
        sd[t] += x;
        __syncthreads();
    }
    int incl = sd[t];
    if (i < N_NODES) indptr[i] = incl - v;   // block-local exclusive
    if (t == 255) bsums[blockIdx.x] = incl;  // block total
}

__global__ void scan2(int* __restrict__ bsums) {
    __shared__ int sd[256];
    int t = threadIdx.x;
    int v = (t < NB_SCAN) ? bsums[t] : 0;
    sd[t] = v;
    __syncthreads();
    for (int o = 1; o < 256; o <<= 1) {
        int x = (t >= o) ? sd[t - o] : 0;
        __syncthreads();
        sd[t] += x;
        __syncthreads();
    }
    if (t < NB_SCAN) bsums[t] = sd[t] - v;   // exclusive block offsets
}

__global__ void scan3(int* __restrict__ indptr, const int* __restrict__ bsums,
                      int* __restrict__ cursor) {
    int i = blockIdx.x * 256 + threadIdx.x;
    if (i < N_NODES) {
        int v = indptr[i] + bsums[blockIdx.x];
        indptr[i] = v;
        cursor[i] = v;
    }
    if (i == 0) indptr[N_NODES] = E_TOT;
}

__global__ void fill_edges(const int* __restrict__ ei, int* __restrict__ cursor,
                           int* __restrict__ esrc, int* __restrict__ edst,
                           const int* __restrict__ flag) {
    int t = blockIdx.x * 256 + threadIdx.x;
    if (t >= E_TOT) return;
    int sh = flag[0] ? 0 : 1;
    int src, dst;
    if (t < E_RAW) { src = ei[t << sh]; dst = ei[(E_RAW + t) << sh]; }
    else           { src = t - E_RAW; dst = src; }
    int pos = atomicAdd(&cursor[dst], 1);
    esrc[pos] = src;
    edst[pos] = dst;
}

// ---------------- GEMM + attention logits (column-split tiles) -------------
// Block = 64 rows x 128 cols (ONE head-pair hb = blockIdx.x & 1; heads
// hb*2, hb*2+1). Grid doubles to 1564 (~6 blocks/CU vs r10's 3 — r10's
// limiter was grid-starved latency hiding: occupancy 20%, VALUBusy 41%).
// r10's proven 2-barrier 32-k chunk loop (r11's register-prefetch pipeline
// SPILLED: WRITE_SIZE 26->70 MB at VGPR=60 — do not re-add live prefetch
// state on top of large acc arrays).
// Thread (da2=t&31, rg=t>>5): rows rg*8..+7, dims d0=2*da2,+1, 2 heads
// -> acc[8][4] = 32 VGPRs. Per k: 2 ds_read_b128 (X bcast) + 2 ds_read_b64
// (W) feed 32 FMA. LDS: xs 8 KB + wsh 16 KB = 24 KB -> 6 blocks/CU.
template <int K>
__global__ void __launch_bounds__(256) gemm_al(
    const float* __restrict__ X, const float* __restrict__ W,
    const float* __restrict__ asrc, const float* __restrict__ adst,
    __half* __restrict__ H, float* __restrict__ AL) {
    __shared__ float xs_t[32 * 64];     // [k-in-chunk][row]
    __shared__ float wsh[32 * 128];     // [k-in-chunk][col-in-half]
    int t = threadIdx.x;
    int n0 = (blockIdx.x >> 1) * 64;
    int hb = blockIdx.x & 1;            // head-pair: global heads hb*2, hb*2+1

    int da2 = t & 31;          // dim pair: d0 = da2*2
    int rg  = t >> 5;          // row group: r0 = rg*8
    int d0 = da2 * 2;
    int r0 = rg * 8;

    float acc[8][4];
#pragma unroll
    for (int i = 0; i < 8; i++)
#pragma unroll
        for (int j = 0; j < 4; j++) acc[i][j] = 0.f;

    const int K4 = K / 4;
    const float4* X4 = (const float4*)X;
    const float4* W4 = (const float4*)W;   // row stride 64 float4
    float4* wsh4 = (float4*)wsh;
    const float2* wsh2 = (const float2*)wsh;

    int xr = t & 63;                    // staging row for this thread
    int xj = t >> 6;                    // staging k4-slot (0..3) per chunk
    int xn = n0 + xr; if (xn >= N_NODES) xn = N_NODES - 1;

    for (int kb = 0; kb < K; kb += 32) {
        __syncthreads();   // previous chunk consumed
        // stage X chunk transposed: 64 rows x 32 k; scatter lane=row (no
        // bank conflicts: consecutive lanes -> consecutive dwords)
#pragma unroll
        for (int c = 0; c < 2; c++) {
            int k4 = xj + 4 * c;        // 0..7 within chunk
            float4 v = X4[(size_t)xn * K4 + (kb >> 2) + k4];
            xs_t[(4 * k4 + 0) * 64 + xr] = v.x;
            xs_t[(4 * k4 + 1) * 64 + xr] = v.y;
            xs_t[(4 * k4 + 2) * 64 + xr] = v.z;
            xs_t[(4 * k4 + 3) * 64 + xr] = v.w;
        }
        // stage W chunk: 32 k-rows x 128 cols (this head-pair) = 1024 float4
#pragma unroll
        for (int m = 0; m < 4; m++) {
            int i = t + 256 * m;
            int kl = i >> 5, c4 = i & 31;   // 32 float4 per k-row
            wsh4[i] = W4[(size_t)(kb + kl) * 64 + hb * 32 + c4];
        }
        __syncthreads();

#pragma unroll 4
        for (int k = 0; k < 32; k++) {
            float4 xa = *(const float4*)&xs_t[k * 64 + r0];
            float4 xb = *(const float4*)&xs_t[k * 64 + r0 + 4];
#pragma unroll
            for (int hh = 0; hh < 2; hh++) {
                float2 w = wsh2[k * 64 + hh * 32 + da2];
                acc[0][2*hh] += xa.x * w.x; acc[0][2*hh+1] += xa.x * w.y;
                acc[1][2*hh] += xa.y * w.x; acc[1][2*hh+1] += xa.y * w.y;
                acc[2][2*hh] += xa.z * w.x; acc[2][2*hh+1] += xa.z * w.y;
                acc[3][2*hh] += xa.w * w.x; acc[3][2*hh+1] += xa.w * w.y;
                acc[4][2*hh] += xb.x * w.x; acc[4][2*hh+1] += xb.x * w.y;
                acc[5][2*hh] += xb.y * w.x; acc[5][2*hh+1] += xb.y * w.y;
                acc[6][2*hh] += xb.z * w.x; acc[6][2*hh+1] += xb.z * w.y;
                acc[7][2*hh] += xb.w * w.x; acc[7][2*hh+1] += xb.w * w.y;
            }
        }
    }

    // H store: fp16 dim-major H[n*256 + d*4 + h]. This block owns heads
    // hb*2..+1 at dims d0,d0+1 -> two __half2 (dword) stores per row.
#pragma unroll
    for (int i = 0; i < 8; i++) {
        int n = n0 + r0 + i;
        if (n < N_NODES) {
            __half2 pa = __float22half2_rn(make_float2(acc[i][0], acc[i][2])); // d0: hh0,hh1
            __half2 pb = __float22half2_rn(make_float2(acc[i][1], acc[i][3])); // d0+1
            *(__half2*)(H + (size_t)n * 256 + d0 * 4 + hb * 2) = pa;
            *(__half2*)(H + (size_t)n * 256 + (d0 + 1) * 4 + hb * 2) = pb;
        }
    }

    // AL: per-row dot for this block's 2 heads, butterfly over 32-lane half.
    const float2* as2 = (const float2*)asrc;
    const float2* ad2 = (const float2*)adst;
    float sp[8][2], dp[8][2];
#pragma unroll
    for (int hh = 0; hh < 2; hh++) {
        int h = hb * 2 + hh;
        float2 av = as2[h * 32 + da2];
        float2 dv = ad2[h * 32 + da2];
#pragma unroll
        for (int i = 0; i < 8; i++) {
            sp[i][hh] = acc[i][2*hh] * av.x + acc[i][2*hh+1] * av.y;
            dp[i][hh] = acc[i][2*hh] * dv.x + acc[i][2*hh+1] * dv.y;
        }
    }
#pragma unroll
    for (int o = 1; o < 32; o <<= 1) {
#pragma unroll
        for (int i = 0; i < 8; i++)
#pragma unroll
            for (int hh = 0; hh < 2; hh++) {
                sp[i][hh] += __shfl_xor(sp[i][hh], o, 64);
                dp[i][hh] += __shfl_xor(dp[i][hh], o, 64);
            }
    }
    if (da2 == 0) {
#pragma unroll
        for (int i = 0; i < 8; i++) {
            int n = n0 + r0 + i;
            if (n < N_NODES) {
#pragma unroll
                for (int hh = 0; hh < 2; hh++) {
                    int h = hb * 2 + hh;
                    AL[n * 8 + h]     = sp[i][hh];
                    AL[n * 8 + 4 + h] = dp[i][hh];
                }
            }
        }
    }
}

// ---------------- Per-edge unnormalized attention weights ----------------
// One thread per CSR edge position: EW[p] = exp(leaky(AL_src + AL_dst)).
// No max shift: logits analytically bounded (validated rounds 4-11).
__global__ void __launch_bounds__(256) edge_weights(
    const float* __restrict__ AL, const int* __restrict__ esrc,
    const int* __restrict__ edst, float4* __restrict__ EW) {
    int p = blockIdx.x * 256 + threadIdx.x;
    if (p >= E_TOT) return;
    int s = esrc[p], d = edst[p];
    const float4* AL4 = (const float4*)AL;
    float4 as = AL4[s * 2];        // src logits (4 heads)
    float4 ad = AL4[d * 2 + 1];    // dst logits (4 heads)
    float v0 = as.x + ad.x; v0 = fmaxf(v0, NEG_SLOPE * v0);
    float v1 = as.y + ad.y; v1 = fmaxf(v1, NEG_SLOPE * v1);
    float v2 = as.z + ad.z; v2 = fmaxf(v2, NEG_SLOPE * v2);
    float v3 = as.w + ad.w; v3 = fmaxf(v3, NEG_SLOPE * v3);
    EW[p] = make_float4(__expf(v0), __expf(v1), __expf(v2), __expf(v3));
}

// ---------------- Per-destination aggregation ----------------
// One wave per dst node. Per edge: one wave-uniform 16 B EW broadcast load
// + one 8 B H gather per lane + 4 FMA / 4 add. Near the L2-miss fetch floor.
__global__ void __launch_bounds__(256) aggregate(
    const __half* __restrict__ H, const float4* __restrict__ EW,
    const int* __restrict__ indptr, const int* __restrict__ esrc,
    const float* __restrict__ bias, float* __restrict__ XOUT) {
    int wave = threadIdx.x >> 6, lane = threadIdx.x & 63;
    int n = blockIdx.x * 4 + wave;   // 12500 * 4 == 50000 exactly

    int start = indptr[n], end = indptr[n + 1];
    const float2* H2 = (const float2*)H;    // 64 float2 per node row

    float d0 = 0.f, d1 = 0.f, d2 = 0.f, d3 = 0.f;
    float a0 = 0.f, a1 = 0.f, a2 = 0.f, a3 = 0.f;

#define EDGE_BODY(E, Hv)                                            \
    {                                                               \
        d0 += E.x; d1 += E.y; d2 += E.z; d3 += E.w;                 \
        float2 c01 = __half22float2(((const __half2*)&Hv)[0]);      \
        float2 c23 = __half22float2(((const __half2*)&Hv)[1]);      \
        a0 += E.x * c01.x; a1 += E.y * c01.y;                       \
        a2 += E.z * c23.x; a3 += E.w * c23.y;                       \
    }

    for (int cb = start; cb < end; cb += 64) {
        int cnt = end - cb; if (cnt > 64) cnt = 64;
        int my_s = (lane < cnt) ? esrc[cb + lane] : 0;
        for (int base = 0; base < cnt; base += 4) {
            int m = cnt - base;   // wave-uniform
            int s0 = __shfl(my_s, base, 64);
            int s1 = __shfl(my_s, base + (1 < m ? 1 : 0), 64);
            int s2 = __shfl(my_s, base + (2 < m ? 2 : 0), 64);
            int s3 = __shfl(my_s, base + (3 < m ? 3 : 0), 64);
            float4 E0 = EW[cb + base];                       // uniform -> bcast
            float4 E1 = EW[cb + base + (1 < m ? 1 : 0)];
            float4 E2 = EW[cb + base + (2 < m ? 2 : 0)];
            float4 E3 = EW[cb + base + (3 < m ? 3 : 0)];
            float2 H0 = H2[(s0 << 6) + lane];
            float2 H1 = H2[(s1 << 6) + lane];
            float2 H2v = H2[(s2 << 6) + lane];
            float2 H3 = H2[(s3 << 6) + lane];
            EDGE_BODY(E0, H0);
            if (m > 1) EDGE_BODY(E1, H1);
            if (m > 2) EDGE_BODY(E2, H2v);
            if (m > 3) EDGE_BODY(E3, H3);
        }
    }
#undef EDGE_BODY

    float r = a0 / d0 + a1 / d1 + a2 / d2 + a3 / d3;
    r = 0.25f * r + bias[lane];
    r = r > 0.f ? r : (__expf(r) - 1.f);   // ELU
    XOUT[n * 64 + lane] = r;
}

// ---------------- Final FC ----------------
__global__ void __launch_bounds__(256) fc_kernel(
    const float* __restrict__ X, const float* __restrict__ fcW,
    const float* __restrict__ fcb, float* __restrict__ OUT) {
    __shared__ float ws[64 * 10];
    __shared__ float bs[10];
    int t = threadIdx.x;
    for (int i = t; i < 640; i += 256) ws[i] = fcW[i];   // 640 > blockDim
    if (t < 10) bs[t] = fcb[t];
    __syncthreads();
    int n = blockIdx.x * 256 + t;
    if (n >= N_NODES) return;
    float acc[10];
#pragma unroll
    for (int c = 0; c < 10; c++) acc[c] = bs[c];
    for (int d = 0; d < 64; d++) {
        float x = X[n * 64 + d];
#pragma unroll
        for (int c = 0; c < 10; c++) acc[c] += x * ws[d * 10 + c];
    }
#pragma unroll
    for (int c = 0; c < 10; c++) OUT[n * 10 + c] = acc[c];
}

// ---------------- Launch ----------------
extern "C" void kernel_launch(void* const* d_in, const int* in_sizes, int n_in,
                              void* d_out, int out_size, void* d_ws, size_t ws_size,
                              hipStream_t stream) {
    const float* x     = (const float*)d_in[0];
    const int*   ei    = (const int*)d_in[1];
    const float* W[3]    = {(const float*)d_in[2], (const float*)d_in[6], (const float*)d_in[10]};
    const float* asrc[3] = {(const float*)d_in[3], (const float*)d_in[7], (const float*)d_in[11]};
    const float* adst[3] = {(const float*)d_in[4], (const float*)d_in[8], (const float*)d_in[12]};
    const float* bias[3] = {(const float*)d_in[5], (const float*)d_in[9], (const float*)d_in[13]};
    const float* fcW = (const float*)d_in[14];
    const float* fcb = (const float*)d_in[15];
    float* out = (float*)d_out;

    char* ws = (char*)d_ws;
    size_t off = 0;
    auto alloc = [&](size_t bytes) {
        void* p = ws + off;
        off = (off + bytes + 255) & ~(size_t)255;
        return p;
    };
    __half* H     = (__half*)alloc((size_t)N_NODES * 256 * 2);  // 25.6 MB fp16
    float* AL     = (float*)alloc((size_t)N_NODES * 8 * 4);     // 1.6 MB
    float4* EW    = (float4*)alloc((size_t)E_TOT * 16);         // 13.6 MB
    float* XA     = (float*)alloc((size_t)N_NODES * 64 * 4);    // 12.8 MB
    float* XB     = (float*)alloc((size_t)N_NODES * 64 * 4);    // 12.8 MB
    int*   counts = (int*)alloc((size_t)N_NODES * 4);
    int*   indptr = (int*)alloc((size_t)(N_NODES + 1) * 4);
    int*   cursor = (int*)alloc((size_t)N_NODES * 4);
    int*   esrc   = (int*)alloc((size_t)E_TOT * 4);             // 3.4 MB
    int*   edst   = (int*)alloc((size_t)E_TOT * 4);             // 3.4 MB
    int*   bsums  = (int*)alloc(256 * 4);
    int*   flag   = (int*)alloc(256 * 4);

    // CSR build (graph is identical each call; ws is re-poisoned so rebuild)
    zero_counts<<<NB_SCAN, 256, 0, stream>>>(counts, flag);
    detect_i32<<<1, 256, 0, stream>>>(ei, flag);
    count_edges<<<NB_EDGE, 256, 0, stream>>>(ei, counts, flag);
    scan1<<<NB_SCAN, 256, 0, stream>>>(counts, indptr, bsums);
    scan2<<<1, 256, 0, stream>>>(bsums);
    scan3<<<NB_SCAN, 256, 0, stream>>>(indptr, bsums, cursor);
    fill_edges<<<NB_EDGE, 256, 0, stream>>>(ei, cursor, esrc, edst, flag);

    // Layer 0
    gemm_al<128><<<NB_GEMM, 256, 0, stream>>>(x, W[0], asrc[0], adst[0], H, AL);
    edge_weights<<<NB_EDGE, 256, 0, stream>>>(AL, esrc, edst, EW);
    aggregate<<<N_NODES / 4, 256, 0, stream>>>(H, EW, indptr, esrc, bias[0], XA);
    // Layer 1
    gemm_al<64><<<NB_GEMM, 256, 0, stream>>>(XA, W[1], asrc[1], adst[1], H, AL);
    edge_weights<<<NB_EDGE, 256, 0, stream>>>(AL, esrc, edst, EW);
    aggregate<<<N_NODES / 4, 256, 0, stream>>>(H, EW, indptr, esrc, bias[1], XB);
    // Layer 2
    gemm_al<64><<<NB_GEMM, 256, 0, stream>>>(XB, W[2], asrc[2], adst[2], H, AL);
    edge_weights<<<NB_EDGE, 256, 0, stream>>>(AL, esrc, edst, EW);
    aggregate<<<N_NODES / 4, 256, 0, stream>>>(H, EW, indptr, esrc, bias[2], XA);

    // Final FC
    fc_kernel<<<NB_SCAN, 256, 0, stream>>>(XA, fcW, fcb, out);
}